// Round 10
// baseline (53.604 us; speedup 1.0000x reference)
//
#include <hip/hip_runtime.h>

#define L_SEQ 4096
#define BATCH 2
#define NHEAD 4
#define DHEAD 32
#define DMODEL 128

typedef __attribute__((ext_vector_type(4))) float floatx4;
typedef __attribute__((ext_vector_type(16))) float floatx16;
typedef __attribute__((ext_vector_type(8))) __bf16 bf16x8;
typedef __attribute__((ext_vector_type(8))) unsigned short ushort8;
typedef __attribute__((ext_vector_type(4))) unsigned int uintx4;

__device__ __forceinline__ floatx4 MFMA(ushort8 a, ushort8 b, floatx4 c) {
  return __builtin_amdgcn_mfma_f32_16x16x32_bf16(
      __builtin_bit_cast(bf16x8, a), __builtin_bit_cast(bf16x8, b), c, 0, 0, 0);
}
__device__ __forceinline__ floatx16 MFMA32(ushort8 a, ushort8 b, floatx16 c) {
  return __builtin_amdgcn_mfma_f32_32x32x16_bf16(
      __builtin_bit_cast(bf16x8, a), __builtin_bit_cast(bf16x8, b), c, 0, 0, 0);
}

__device__ __forceinline__ unsigned short f2bf(float f) {
  union { float f; unsigned int u; } x; x.f = f;
  unsigned int u = x.u + 0x7fffu + ((x.u >> 16) & 1u);   // RNE truncate
  return (unsigned short)(u >> 16);
}

__device__ __forceinline__ unsigned pkbf(float lo, float hi) {
  unsigned r;
  asm("v_cvt_pk_bf16_f32 %0, %1, %2" : "=v"(r) : "v"(lo), "v"(hi));
  return r;
}

// ---------------------------------------------------------------------------
// Kernel 1: fused QKV projection.  out = x @ W^T + b  (Q also * 1/sqrt(32))
// Q stored natural [plane][L][32] bf16.
// K,V stored FRAGMENT-PACKED per 64-kv tile: [plane][t][frag 0..3][lane][8]
// so attn's per-lane ushort8 loads are base + lane*16B (fully coalesced).
// ---------------------------------------------------------------------------
#define WLDS 136

__global__ __launch_bounds__(256) void proj_kernel(
    const float* __restrict__ xq, const float* __restrict__ xk,
    const float* __restrict__ xv,
    const float* __restrict__ WQ, const float* __restrict__ bQ,
    const float* __restrict__ WK, const float* __restrict__ bK,
    const float* __restrict__ WV, const float* __restrict__ bV,
    unsigned short* __restrict__ Qs, unsigned short* __restrict__ Ks,
    unsigned short* __restrict__ Vt)
{
  __shared__ unsigned short Wl[128 * WLDS];
  __shared__ float bl[128];
  const int mat = blockIdx.z;
  const int b   = blockIdx.y;
  const int l0  = blockIdx.x * 64;
  const float* __restrict__ x    = (mat == 0) ? xq : (mat == 1) ? xk : xv;
  const float* __restrict__ W    = (mat == 0) ? WQ : (mat == 1) ? WK : WV;
  const float* __restrict__ bias = (mat == 0) ? bQ : (mat == 1) ? bK : bV;
  const int tid = threadIdx.x;

  #pragma unroll
  for (int it = 0; it < 16; ++it) {
    int idx = tid + it * 256;
    int row = idx >> 5;
    int col = (idx & 31) * 4;
    floatx4 v = *(const floatx4*)(W + row * 128 + col);
    unsigned short* dst = Wl + row * WLDS + col;
    dst[0] = f2bf(v[0]); dst[1] = f2bf(v[1]);
    dst[2] = f2bf(v[2]); dst[3] = f2bf(v[3]);
  }
  if (tid < 128) bl[tid] = bias[tid];
  __syncthreads();

  const int w = tid >> 6, lane = tid & 63;
  const int g = lane >> 4, qi = lane & 15;

  ushort8 xf[4];
  #pragma unroll
  for (int kk = 0; kk < 4; ++kk) {
    const float* src = x + ((size_t)(l0 + w * 16 + qi) * BATCH + b) * DMODEL + kk * 32 + g * 8;
    floatx4 a = *(const floatx4*)src;
    floatx4 c = *(const floatx4*)(src + 4);
    ushort8 f;
    f[0]=f2bf(a[0]); f[1]=f2bf(a[1]); f[2]=f2bf(a[2]); f[3]=f2bf(a[3]);
    f[4]=f2bf(c[0]); f[5]=f2bf(c[1]); f[6]=f2bf(c[2]); f[7]=f2bf(c[3]);
    xf[kk] = f;
  }

  floatx4 acc[8];
  #pragma unroll
  for (int n = 0; n < 8; ++n) acc[n] = (floatx4){0.f, 0.f, 0.f, 0.f};

  #pragma unroll
  for (int kk = 0; kk < 4; ++kk) {
    #pragma unroll
    for (int n = 0; n < 8; ++n) {
      ushort8 wf = *(const ushort8*)(Wl + (n * 16 + qi) * WLDS + kk * 32 + g * 8);
      acc[n] = (mat == 2) ? MFMA(wf, xf[kk], acc[n]) : MFMA(xf[kk], wf, acc[n]);
    }
  }

  const int hb4 = b * NHEAD;
  if (mat == 0) {
    const float scale = 0.17677669529663687f;  // 32^-0.5
    #pragma unroll
    for (int n = 0; n < 8; ++n) {
      int c = n * 16 + qi;
      int h = c >> 5, dh = c & 31;
      float bb = bl[c];
      #pragma unroll
      for (int r = 0; r < 4; ++r) {
        int lq = l0 + w * 16 + 4 * g + r;
        float v = (acc[n][r] + bb) * scale;
        Qs[((size_t)(hb4 + h) * L_SEQ + lq) * DHEAD + dh] = f2bf(v);
      }
    }
  } else if (mat == 1) {
    // K fragment-packed
    #pragma unroll
    for (int n = 0; n < 8; ++n) {
      int c = n * 16 + qi;
      int h = c >> 5, dh = c & 31;
      int dj  = (dh >> 4) & 1;
      int hi2 = (dh >> 3) & 1;
      int e   = dh & 7;
      float bb = bl[c];
      #pragma unroll
      for (int r = 0; r < 4; ++r) {
        int lq = l0 + w * 16 + 4 * g + r;
        int t   = lq >> 6;
        int rr  = lq & 63;
        int ql2 = rr & 31, rhi = rr >> 5;
        size_t off = ((((size_t)(hb4 + h) * 64 + t) * 4 + (2 * rhi + dj)) * 64
                      + (hi2 * 32 + ql2)) * 8 + e;
        Ks[off] = f2bf(acc[n][r] + bb);
      }
    }
  } else {
    // V fragment-packed
    #pragma unroll
    for (int n = 0; n < 8; ++n) {
      #pragma unroll
      for (int r = 0; r < 4; ++r) {
        int cout = n * 16 + 4 * g + r;
        int h = cout >> 5, dh2 = cout & 31;
        float v = acc[n][r] + bl[cout];
        int lq  = l0 + w * 16 + qi;
        int t   = lq >> 6;
        int kvt = lq & 63;
        int s   = kvt >> 4;
        int u   = kvt & 15;
        int b2  = (u >> 3) & 1;
        int hi2 = (u >> 2) & 1;
        int e2  = u & 3;
        size_t off = ((((size_t)(hb4 + h) * 64 + t) * 4 + s) * 64
                      + (hi2 * 32 + dh2)) * 8 + (4 * b2 + e2);
        Vt[off] = f2bf(v);
      }
    }
  }
}

// ---------------------------------------------------------------------------
// Kernel 2: KV-split flash attention, 32x32 MFMA, fully lane-local softmax.
// R10 change (balance only): block = one q-tile tq; its 4 waves split
// [0, tq+1) into 4 EQUAL-width chunks (width = tq/4+1). Waves whose chunk is
// empty still write identity partials (m=-1e30, l=0, acc=0) which combine
// weights to zero. Slots, ws layout, math, epilogue identical to green R9.
// Grid (64, 16): x = tq, y = plane*2 + half.
// ---------------------------------------------------------------------------
__global__ __launch_bounds__(256, 4) void attn_kernel(
    const unsigned short* __restrict__ Qs, const unsigned short* __restrict__ Ks,
    const unsigned short* __restrict__ Vt,
    float* __restrict__ Opart, float* __restrict__ MLpart)
{
  __shared__ float Tr[4][32 * 36];   // per-wave transpose scratch

  const int tid = threadIdx.x;
  const int w = tid >> 6, lane = tid & 63;
  const int ql = lane & 31, hi = lane >> 5;

  const int tq    = blockIdx.x;              // 0..63
  const int plane = blockIdx.y >> 1;
  const int half  = blockIdx.y & 1;

  const int c     = w;                       // chunk index = wave id
  const int width = (tq >> 2) + 1;           // ceil((tq+1)/4)
  const int t0    = c * width;
  const int tend  = min(t0 + width, tq + 1); // may be <= t0 (empty)

  const unsigned short* __restrict__ Qh = Qs + (size_t)plane * L_SEQ * DHEAD;

  const int q0 = tq * 64 + half * 32;
  // Q B-frags: lane holds Q[q0+ql][dhalf*16 + hi*8 + 0..7]
  ushort8 qf0 = *(const ushort8*)(Qh + (size_t)(q0 + ql) * DHEAD + hi * 8);
  ushort8 qf1 = *(const ushort8*)(Qh + (size_t)(q0 + ql) * DHEAD + 16 + hi * 8);

  const floatx16 z16 = {0,0,0,0,0,0,0,0,0,0,0,0,0,0,0,0};
  floatx16 acc = z16;          // O^T[dh=(r&3)+8*(r>>2)+4*hi][q=ql]
  float m = -1e30f, l = 0.f;

  // fragment-packed tile base pointers (advance 2048 ush per tile)
  const unsigned short* kb = Ks + ((size_t)plane * 64 + t0) * 2048 + (size_t)lane * 8;
  const unsigned short* vb = Vt + ((size_t)plane * 64 + t0) * 2048 + (size_t)lane * 8;

  for (int t = t0; t < tend; ++t) {
    // ---- loads: 8 x fully-coalesced 16B/lane ----
    ushort8 kf00 = *(const ushort8*)(kb);           // j0: rows 0-31,  d 0..15
    ushort8 kf01 = *(const ushort8*)(kb + 512);     // j1: rows 0-31,  d 16..31
    ushort8 kf10 = *(const ushort8*)(kb + 1024);    // j2: rows 32-63, d 0..15
    ushort8 kf11 = *(const ushort8*)(kb + 1536);    // j3: rows 32-63, d 16..31
    ushort8 va0  = *(const ushort8*)(vb);           // s0: kv 0..15
    ushort8 va1  = *(const ushort8*)(vb + 512);     // s1: kv 16..31
    ushort8 va2  = *(const ushort8*)(vb + 1024);    // s2: kv 32..47
    ushort8 va3  = *(const ushort8*)(vb + 1536);    // s3: kv 48..63
    kb += 2048;
    vb += 2048;

    // ---- QK^T: St[kg][row kv'=(r&3)+8*(r>>2)+4*hi][col q=ql] ----
    floatx16 St0 = MFMA32(kf00, qf0, z16);
    St0 = MFMA32(kf01, qf1, St0);
    floatx16 St1 = MFMA32(kf10, qf0, z16);
    St1 = MFMA32(kf11, qf1, St1);

    // ---- lane-local softmax (column q = ql) ----
    float pmax = St0[0];
    #pragma unroll
    for (int i = 1; i < 16; ++i) pmax = fmaxf(pmax, St0[i]);
    #pragma unroll
    for (int i = 0; i < 16; ++i) pmax = fmaxf(pmax, St1[i]);
    pmax = fmaxf(pmax, __shfl_xor(pmax, 32));

    if (__any(pmax > m + 8.0f)) {            // defer-max (THR=8)
      float mnew = fmaxf(m, pmax);
      float corr = __expf(m - mnew);
      m = mnew;
      l *= corr;
      #pragma unroll
      for (int i = 0; i < 16; ++i) acc[i] *= corr;
    }
    float rsum = 0.f;
    #pragma unroll
    for (int i = 0; i < 16; ++i) { float e = __expf(St0[i] - m); St0[i] = e; rsum += e; }
    #pragma unroll
    for (int i = 0; i < 16; ++i) { float e = __expf(St1[i] - m); St1[i] = e; rsum += e; }
    rsum += __shfl_xor(rsum, 32);
    l += rsum;

    // ---- pack P (own lanes only; kv order matches packed V frags) ----
    uintx4 pb;
    // kg0 sub0: p rows St0[0..7]
    pb[0] = pkbf(St0[0], St0[1]); pb[1] = pkbf(St0[2], St0[3]);
    pb[2] = pkbf(St0[4], St0[5]); pb[3] = pkbf(St0[6], St0[7]);
    acc = MFMA32(va0, __builtin_bit_cast(ushort8, pb), acc);
    // kg0 sub1: St0[8..15]
    pb[0] = pkbf(St0[8], St0[9]);  pb[1] = pkbf(St0[10], St0[11]);
    pb[2] = pkbf(St0[12], St0[13]); pb[3] = pkbf(St0[14], St0[15]);
    acc = MFMA32(va1, __builtin_bit_cast(ushort8, pb), acc);
    // kg1 sub0: St1[0..7]
    pb[0] = pkbf(St1[0], St1[1]); pb[1] = pkbf(St1[2], St1[3]);
    pb[2] = pkbf(St1[4], St1[5]); pb[3] = pkbf(St1[6], St1[7]);
    acc = MFMA32(va2, __builtin_bit_cast(ushort8, pb), acc);
    // kg1 sub1: St1[8..15]
    pb[0] = pkbf(St1[8], St1[9]);  pb[1] = pkbf(St1[10], St1[11]);
    pb[2] = pkbf(St1[12], St1[13]); pb[3] = pkbf(St1[14], St1[15]);
    acc = MFMA32(va3, __builtin_bit_cast(ushort8, pb), acc);
  }

  // ---- epilogue: transpose O^T -> O via LDS, write f32 partials ----
  const int slot = ((plane * 64 + tq) * 4 + c);
  float* T = &Tr[w][0];
  #pragma unroll
  for (int r = 0; r < 16; ++r) {
    int dh = (r & 3) + 8 * (r >> 2) + 4 * hi;
    T[ql * 36 + dh] = acc[r];
  }
  asm volatile("s_waitcnt lgkmcnt(0)" ::: "memory");
  __builtin_amdgcn_sched_barrier(0);

  const int qr = lane >> 1, dg = (lane & 1) * 16;
  float* __restrict__ Op = Opart + (size_t)slot * 2048 + half * 32 * 32;
  #pragma unroll
  for (int j = 0; j < 4; ++j) {
    floatx4 vv = *(const floatx4*)(T + qr * 36 + dg + 4 * j);
    *(floatx4*)(Op + qr * 32 + dg + 4 * j) = vv;
  }
  if (hi == 0) {
    MLpart[(size_t)slot * 128 + (half * 32 + ql) * 2 + 0] = m;
    MLpart[(size_t)slot * 128 + (half * 32 + ql) * 2 + 1] = l;
  }
}

// ---------------------------------------------------------------------------
// Kernel 2b: combine partials -> ctx bf16 [B][L][128]
// Always 4 slots per tq now (empty chunks carry m=-1e30, l=0 -> weight 0).
// Grid (64, 8), 256 threads: thread = (q row 0..63) x (dh-group of 8)
// ---------------------------------------------------------------------------
__global__ __launch_bounds__(256) void combine_kernel(
    const float* __restrict__ Opart, const float* __restrict__ MLpart,
    unsigned short* __restrict__ ctx)
{
  const int tq = blockIdx.x;
  const int hb = blockIdx.y;
  const int tid = threadIdx.x;
  const int q  = tid >> 2;
  const int dg = tid & 3;
  const int slot0 = (hb * 64 + tq) * 4;

  float mv[4], lv[4];
  float M = -1e30f;
  #pragma unroll
  for (int ci = 0; ci < 4; ++ci) {
    mv[ci] = MLpart[(size_t)(slot0 + ci) * 128 + q * 2 + 0];
    lv[ci] = MLpart[(size_t)(slot0 + ci) * 128 + q * 2 + 1];
    M = fmaxf(M, mv[ci]);
  }
  float Lsum = 0.f;
  float wgt[4];
  #pragma unroll
  for (int ci = 0; ci < 4; ++ci) {
    wgt[ci] = __expf(mv[ci] - M);
    Lsum += wgt[ci] * lv[ci];
  }
  float inv = 1.0f / Lsum;

  floatx4 a0 = (floatx4){0.f,0.f,0.f,0.f}, a1 = (floatx4){0.f,0.f,0.f,0.f};
  #pragma unroll
  for (int ci = 0; ci < 4; ++ci) {
    const float* Op = Opart + (size_t)(slot0 + ci) * 2048 + q * 32 + dg * 8;
    floatx4 o0 = *(const floatx4*)(Op);
    floatx4 o1 = *(const floatx4*)(Op + 4);
    float wv = wgt[ci];
    a0 += wv * o0;
    a1 += wv * o1;
  }
  const int b = hb >> 2, hh = hb & 3;
  size_t base = ((size_t)b * L_SEQ + tq * 64 + q) * DMODEL + hh * 32 + dg * 8;
  #pragma unroll
  for (int j = 0; j < 4; ++j) {
    ctx[base + j]     = f2bf(a0[j] * inv);
    ctx[base + 4 + j] = f2bf(a1[j] * inv);
  }
}

// ---------------------------------------------------------------------------
// Kernel 3: output projection  out = ctx @ W_O^T + b_O  (f32 out)
// ---------------------------------------------------------------------------
__global__ __launch_bounds__(256) void oproj_kernel(
    const unsigned short* __restrict__ ctx, const float* __restrict__ WO,
    const float* __restrict__ bO, float* __restrict__ out)
{
  __shared__ unsigned short Wl[128 * WLDS];
  __shared__ float bl[128];
  const int m0 = blockIdx.x * 64;
  const int tid = threadIdx.x;

  #pragma unroll
  for (int it = 0; it < 16; ++it) {
    int idx = tid + it * 256;
    int row = idx >> 5, col = (idx & 31) * 4;
    floatx4 v = *(const floatx4*)(WO + row * 128 + col);
    unsigned short* dst = Wl + row * WLDS + col;
    dst[0] = f2bf(v[0]); dst[1] = f2bf(v[1]);
    dst[2] = f2bf(v[2]); dst[3] = f2bf(v[3]);
  }
  if (tid < 128) bl[tid] = bO[tid];
  __syncthreads();

  const int w = tid >> 6, lane = tid & 63;
  const int g = lane >> 4, qi = lane & 15;

  ushort8 xf[4];
  #pragma unroll
  for (int kk = 0; kk < 4; ++kk)
    xf[kk] = *(const ushort8*)(ctx + (size_t)(m0 + w * 16 + qi) * DMODEL + kk * 32 + g * 8);

  floatx4 acc[8];
  #pragma unroll
  for (int n = 0; n < 8; ++n) acc[n] = (floatx4){0.f, 0.f, 0.f, 0.f};

  #pragma unroll
  for (int kk = 0; kk < 4; ++kk) {
    #pragma unroll
    for (int n = 0; n < 8; ++n) {
      ushort8 wf = *(const ushort8*)(Wl + (n * 16 + qi) * WLDS + kk * 32 + g * 8);
      acc[n] = MFMA(xf[kk], wf, acc[n]);
    }
  }

  #pragma unroll
  for (int n = 0; n < 8; ++n) {
    int c = n * 16 + qi;
    float bb = bl[c];
    #pragma unroll
    for (int r = 0; r < 4; ++r) {
      int m = m0 + w * 16 + 4 * g + r;
      out[(size_t)m * DMODEL + c] = acc[n][r] + bb;
    }
  }
}

// ---------------------------------------------------------------------------
extern "C" void kernel_launch(void* const* d_in, const int* in_sizes, int n_in,
                              void* d_out, int out_size, void* d_ws, size_t ws_size,
                              hipStream_t stream) {
  const float* q  = (const float*)d_in[0];
  const float* k  = (const float*)d_in[1];
  const float* v  = (const float*)d_in[2];
  const float* WQ = (const float*)d_in[3];
  const float* bQ = (const float*)d_in[4];
  const float* WK = (const float*)d_in[5];
  const float* bK = (const float*)d_in[6];
  const float* WV = (const float*)d_in[7];
  const float* bV = (const float*)d_in[8];
  const float* WO = (const float*)d_in[9];
  const float* bO = (const float*)d_in[10];
  float* out = (float*)d_out;

  const size_t plane = (size_t)BATCH * NHEAD * L_SEQ * DHEAD;  // 1,048,576 ush
  unsigned short* Qs  = (unsigned short*)d_ws;
  unsigned short* Ks  = Qs + plane;
  unsigned short* Vt  = Ks + plane;
  unsigned short* ctx = Vt + plane;                 // [B][L][128] bf16 (1M ush)
  float* Opart  = (float*)(ctx + plane);            // 2048 slots x 64 x 32 f32
  float* MLpart = Opart + (size_t)2048 * 2048;      // 2048 slots x 64 x 2 f32

  hipLaunchKernelGGL(proj_kernel, dim3(64, 2, 3), dim3(256), 0, stream,
                     q, k, v, WQ, bQ, WK, bK, WV, bV, Qs, Ks, Vt);
  hipLaunchKernelGGL(attn_kernel, dim3(64, 16), dim3(256), 0, stream,
                     Qs, Ks, Vt, Opart, MLpart);
  hipLaunchKernelGGL(combine_kernel, dim3(64, 8), dim3(256), 0, stream,
                     Opart, MLpart, ctx);
  hipLaunchKernelGGL(oproj_kernel, dim3(128), dim3(256), 0, stream, ctx, WO, bO, out);
}

// Round 11
// 42.462 us; speedup vs baseline: 1.2624x; 1.2624x over previous
//
#include <hip/hip_runtime.h>

#define L_SEQ 4096
#define BATCH 2
#define NHEAD 4
#define DHEAD 32
#define DMODEL 128

typedef __attribute__((ext_vector_type(4))) float floatx4;
typedef __attribute__((ext_vector_type(16))) float floatx16;
typedef __attribute__((ext_vector_type(8))) __bf16 bf16x8;
typedef __attribute__((ext_vector_type(8))) unsigned short ushort8;
typedef __attribute__((ext_vector_type(4))) unsigned int uintx4;

__device__ __forceinline__ floatx4 MFMA(ushort8 a, ushort8 b, floatx4 c) {
  return __builtin_amdgcn_mfma_f32_16x16x32_bf16(
      __builtin_bit_cast(bf16x8, a), __builtin_bit_cast(bf16x8, b), c, 0, 0, 0);
}
__device__ __forceinline__ floatx16 MFMA32(ushort8 a, ushort8 b, floatx16 c) {
  return __builtin_amdgcn_mfma_f32_32x32x16_bf16(
      __builtin_bit_cast(bf16x8, a), __builtin_bit_cast(bf16x8, b), c, 0, 0, 0);
}

__device__ __forceinline__ unsigned short f2bf(float f) {
  union { float f; unsigned int u; } x; x.f = f;
  unsigned int u = x.u + 0x7fffu + ((x.u >> 16) & 1u);   // RNE truncate
  return (unsigned short)(u >> 16);
}

__device__ __forceinline__ unsigned pkbf(float lo, float hi) {
  unsigned r;
  asm("v_cvt_pk_bf16_f32 %0, %1, %2" : "=v"(r) : "v"(lo), "v"(hi));
  return r;
}

// ---------------------------------------------------------------------------
// Kernel 1: fused QKV projection.  out = x @ W^T + b  (Q also * 1/sqrt(32))
// Q stored natural [plane][L][32] bf16.
// K,V stored FRAGMENT-PACKED per 64-kv tile: [plane][t][frag 0..3][lane][8]
// so attn's per-lane ushort8 loads are base + lane*16B (fully coalesced).
// ---------------------------------------------------------------------------
#define WLDS 136

__global__ __launch_bounds__(256) void proj_kernel(
    const float* __restrict__ xq, const float* __restrict__ xk,
    const float* __restrict__ xv,
    const float* __restrict__ WQ, const float* __restrict__ bQ,
    const float* __restrict__ WK, const float* __restrict__ bK,
    const float* __restrict__ WV, const float* __restrict__ bV,
    unsigned short* __restrict__ Qs, unsigned short* __restrict__ Ks,
    unsigned short* __restrict__ Vt)
{
  __shared__ unsigned short Wl[128 * WLDS];
  __shared__ float bl[128];
  const int mat = blockIdx.z;
  const int b   = blockIdx.y;
  const int l0  = blockIdx.x * 64;
  const float* __restrict__ x    = (mat == 0) ? xq : (mat == 1) ? xk : xv;
  const float* __restrict__ W    = (mat == 0) ? WQ : (mat == 1) ? WK : WV;
  const float* __restrict__ bias = (mat == 0) ? bQ : (mat == 1) ? bK : bV;
  const int tid = threadIdx.x;

  #pragma unroll
  for (int it = 0; it < 16; ++it) {
    int idx = tid + it * 256;
    int row = idx >> 5;
    int col = (idx & 31) * 4;
    floatx4 v = *(const floatx4*)(W + row * 128 + col);
    unsigned short* dst = Wl + row * WLDS + col;
    dst[0] = f2bf(v[0]); dst[1] = f2bf(v[1]);
    dst[2] = f2bf(v[2]); dst[3] = f2bf(v[3]);
  }
  if (tid < 128) bl[tid] = bias[tid];
  __syncthreads();

  const int w = tid >> 6, lane = tid & 63;
  const int g = lane >> 4, qi = lane & 15;

  ushort8 xf[4];
  #pragma unroll
  for (int kk = 0; kk < 4; ++kk) {
    const float* src = x + ((size_t)(l0 + w * 16 + qi) * BATCH + b) * DMODEL + kk * 32 + g * 8;
    floatx4 a = *(const floatx4*)src;
    floatx4 c = *(const floatx4*)(src + 4);
    ushort8 f;
    f[0]=f2bf(a[0]); f[1]=f2bf(a[1]); f[2]=f2bf(a[2]); f[3]=f2bf(a[3]);
    f[4]=f2bf(c[0]); f[5]=f2bf(c[1]); f[6]=f2bf(c[2]); f[7]=f2bf(c[3]);
    xf[kk] = f;
  }

  floatx4 acc[8];
  #pragma unroll
  for (int n = 0; n < 8; ++n) acc[n] = (floatx4){0.f, 0.f, 0.f, 0.f};

  #pragma unroll
  for (int kk = 0; kk < 4; ++kk) {
    #pragma unroll
    for (int n = 0; n < 8; ++n) {
      ushort8 wf = *(const ushort8*)(Wl + (n * 16 + qi) * WLDS + kk * 32 + g * 8);
      acc[n] = (mat == 2) ? MFMA(wf, xf[kk], acc[n]) : MFMA(xf[kk], wf, acc[n]);
    }
  }

  const int hb4 = b * NHEAD;
  if (mat == 0) {
    const float scale = 0.17677669529663687f;  // 32^-0.5
    #pragma unroll
    for (int n = 0; n < 8; ++n) {
      int c = n * 16 + qi;
      int h = c >> 5, dh = c & 31;
      float bb = bl[c];
      #pragma unroll
      for (int r = 0; r < 4; ++r) {
        int lq = l0 + w * 16 + 4 * g + r;
        float v = (acc[n][r] + bb) * scale;
        Qs[((size_t)(hb4 + h) * L_SEQ + lq) * DHEAD + dh] = f2bf(v);
      }
    }
  } else if (mat == 1) {
    // K fragment-packed
    #pragma unroll
    for (int n = 0; n < 8; ++n) {
      int c = n * 16 + qi;
      int h = c >> 5, dh = c & 31;
      int dj  = (dh >> 4) & 1;
      int hi2 = (dh >> 3) & 1;
      int e   = dh & 7;
      float bb = bl[c];
      #pragma unroll
      for (int r = 0; r < 4; ++r) {
        int lq = l0 + w * 16 + 4 * g + r;
        int t   = lq >> 6;
        int rr  = lq & 63;
        int ql2 = rr & 31, rhi = rr >> 5;
        size_t off = ((((size_t)(hb4 + h) * 64 + t) * 4 + (2 * rhi + dj)) * 64
                      + (hi2 * 32 + ql2)) * 8 + e;
        Ks[off] = f2bf(acc[n][r] + bb);
      }
    }
  } else {
    // V fragment-packed
    #pragma unroll
    for (int n = 0; n < 8; ++n) {
      #pragma unroll
      for (int r = 0; r < 4; ++r) {
        int cout = n * 16 + 4 * g + r;
        int h = cout >> 5, dh2 = cout & 31;
        float v = acc[n][r] + bl[cout];
        int lq  = l0 + w * 16 + qi;
        int t   = lq >> 6;
        int kvt = lq & 63;
        int s   = kvt >> 4;
        int u   = kvt & 15;
        int b2  = (u >> 3) & 1;
        int hi2 = (u >> 2) & 1;
        int e2  = u & 3;
        size_t off = ((((size_t)(hb4 + h) * 64 + t) * 4 + s) * 64
                      + (hi2 * 32 + dh2)) * 8 + (4 * b2 + e2);
        Vt[off] = f2bf(v);
      }
    }
  }
}

// ---------------------------------------------------------------------------
// Kernel 2: KV-split flash attention, 32x32 MFMA, fully lane-local softmax.
// R11 change (mapping only): grid (16, 64); x = plane-half, y = j.
// Same-CU blocks differ by j+=16 (linear stride 256 ≡ same CU), so map
// tq = [b, 63-b, 16+b, 47-b][j>>4] (b = j&15): per-wave lengths over the
// quartet sum to a CONSTANT 34 steps -> every CU gets identical load.
// Block = one q-tile; 4 waves split [0,tq+1) into equal chunks (R10 body).
// ---------------------------------------------------------------------------
__global__ __launch_bounds__(256, 4) void attn_kernel(
    const unsigned short* __restrict__ Qs, const unsigned short* __restrict__ Ks,
    const unsigned short* __restrict__ Vt,
    float* __restrict__ Opart, float* __restrict__ MLpart)
{
  __shared__ float Tr[4][32 * 36];   // per-wave transpose scratch

  const int tid = threadIdx.x;
  const int w = tid >> 6, lane = tid & 63;
  const int ql = lane & 31, hi = lane >> 5;

  const int ph    = blockIdx.x;              // 0..15
  const int plane = ph >> 1;
  const int half  = ph & 1;
  const int j     = blockIdx.y;              // 0..63
  const int bq    = j & 15, mq = j >> 4;
  const int tq    = (mq == 0) ? bq : (mq == 1) ? 63 - bq
                  : (mq == 2) ? 16 + bq : 47 - bq;

  const int c     = w;                       // chunk index = wave id
  const int width = (tq >> 2) + 1;           // ceil((tq+1)/4)
  const int t0    = c * width;
  const int tend  = min(t0 + width, tq + 1); // may be <= t0 (empty)

  const unsigned short* __restrict__ Qh = Qs + (size_t)plane * L_SEQ * DHEAD;

  const int q0 = tq * 64 + half * 32;
  // Q B-frags: lane holds Q[q0+ql][dhalf*16 + hi*8 + 0..7]
  ushort8 qf0 = *(const ushort8*)(Qh + (size_t)(q0 + ql) * DHEAD + hi * 8);
  ushort8 qf1 = *(const ushort8*)(Qh + (size_t)(q0 + ql) * DHEAD + 16 + hi * 8);

  const floatx16 z16 = {0,0,0,0,0,0,0,0,0,0,0,0,0,0,0,0};
  floatx16 acc = z16;          // O^T[dh=(r&3)+8*(r>>2)+4*hi][q=ql]
  float m = -1e30f, l = 0.f;

  // fragment-packed tile base pointers (advance 2048 ush per tile)
  const unsigned short* kb = Ks + ((size_t)plane * 64 + t0) * 2048 + (size_t)lane * 8;
  const unsigned short* vb = Vt + ((size_t)plane * 64 + t0) * 2048 + (size_t)lane * 8;

  for (int t = t0; t < tend; ++t) {
    // ---- loads: 8 x fully-coalesced 16B/lane ----
    ushort8 kf00 = *(const ushort8*)(kb);           // j0: rows 0-31,  d 0..15
    ushort8 kf01 = *(const ushort8*)(kb + 512);     // j1: rows 0-31,  d 16..31
    ushort8 kf10 = *(const ushort8*)(kb + 1024);    // j2: rows 32-63, d 0..15
    ushort8 kf11 = *(const ushort8*)(kb + 1536);    // j3: rows 32-63, d 16..31
    ushort8 va0  = *(const ushort8*)(vb);           // s0: kv 0..15
    ushort8 va1  = *(const ushort8*)(vb + 512);     // s1: kv 16..31
    ushort8 va2  = *(const ushort8*)(vb + 1024);    // s2: kv 32..47
    ushort8 va3  = *(const ushort8*)(vb + 1536);    // s3: kv 48..63
    kb += 2048;
    vb += 2048;

    // ---- QK^T: St[kg][row kv'=(r&3)+8*(r>>2)+4*hi][col q=ql] ----
    floatx16 St0 = MFMA32(kf00, qf0, z16);
    St0 = MFMA32(kf01, qf1, St0);
    floatx16 St1 = MFMA32(kf10, qf0, z16);
    St1 = MFMA32(kf11, qf1, St1);

    // ---- lane-local softmax (column q = ql) ----
    float pmax = St0[0];
    #pragma unroll
    for (int i = 1; i < 16; ++i) pmax = fmaxf(pmax, St0[i]);
    #pragma unroll
    for (int i = 0; i < 16; ++i) pmax = fmaxf(pmax, St1[i]);
    pmax = fmaxf(pmax, __shfl_xor(pmax, 32));

    if (__any(pmax > m + 8.0f)) {            // defer-max (THR=8)
      float mnew = fmaxf(m, pmax);
      float corr = __expf(m - mnew);
      m = mnew;
      l *= corr;
      #pragma unroll
      for (int i = 0; i < 16; ++i) acc[i] *= corr;
    }
    float rsum = 0.f;
    #pragma unroll
    for (int i = 0; i < 16; ++i) { float e = __expf(St0[i] - m); St0[i] = e; rsum += e; }
    #pragma unroll
    for (int i = 0; i < 16; ++i) { float e = __expf(St1[i] - m); St1[i] = e; rsum += e; }
    rsum += __shfl_xor(rsum, 32);
    l += rsum;

    // ---- pack P (own lanes only; kv order matches packed V frags) ----
    uintx4 pb;
    // kg0 sub0: p rows St0[0..7]
    pb[0] = pkbf(St0[0], St0[1]); pb[1] = pkbf(St0[2], St0[3]);
    pb[2] = pkbf(St0[4], St0[5]); pb[3] = pkbf(St0[6], St0[7]);
    acc = MFMA32(va0, __builtin_bit_cast(ushort8, pb), acc);
    // kg0 sub1: St0[8..15]
    pb[0] = pkbf(St0[8], St0[9]);  pb[1] = pkbf(St0[10], St0[11]);
    pb[2] = pkbf(St0[12], St0[13]); pb[3] = pkbf(St0[14], St0[15]);
    acc = MFMA32(va1, __builtin_bit_cast(ushort8, pb), acc);
    // kg1 sub0: St1[0..7]
    pb[0] = pkbf(St1[0], St1[1]); pb[1] = pkbf(St1[2], St1[3]);
    pb[2] = pkbf(St1[4], St1[5]); pb[3] = pkbf(St1[6], St1[7]);
    acc = MFMA32(va2, __builtin_bit_cast(ushort8, pb), acc);
    // kg1 sub1: St1[8..15]
    pb[0] = pkbf(St1[8], St1[9]);  pb[1] = pkbf(St1[10], St1[11]);
    pb[2] = pkbf(St1[12], St1[13]); pb[3] = pkbf(St1[14], St1[15]);
    acc = MFMA32(va3, __builtin_bit_cast(ushort8, pb), acc);
  }

  // ---- epilogue: transpose O^T -> O via LDS, write f32 partials ----
  const int slot = ((plane * 64 + tq) * 4 + c);
  float* T = &Tr[w][0];
  #pragma unroll
  for (int r = 0; r < 16; ++r) {
    int dh = (r & 3) + 8 * (r >> 2) + 4 * hi;
    T[ql * 36 + dh] = acc[r];
  }
  asm volatile("s_waitcnt lgkmcnt(0)" ::: "memory");
  __builtin_amdgcn_sched_barrier(0);

  const int qr = lane >> 1, dg = (lane & 1) * 16;
  float* __restrict__ Op = Opart + (size_t)slot * 2048 + half * 32 * 32;
  #pragma unroll
  for (int j2 = 0; j2 < 4; ++j2) {
    floatx4 vv = *(const floatx4*)(T + qr * 36 + dg + 4 * j2);
    *(floatx4*)(Op + qr * 32 + dg + 4 * j2) = vv;
  }
  if (hi == 0) {
    MLpart[(size_t)slot * 128 + (half * 32 + ql) * 2 + 0] = m;
    MLpart[(size_t)slot * 128 + (half * 32 + ql) * 2 + 1] = l;
  }
}

// ---------------------------------------------------------------------------
// Kernel 2b: combine partials -> ctx bf16 [B][L][128]
// Always 4 slots per tq (empty chunks carry m=-1e30, l=0 -> weight 0).
// Grid (64, 8), 256 threads: thread = (q row 0..63) x (dh-group of 8)
// ---------------------------------------------------------------------------
__global__ __launch_bounds__(256) void combine_kernel(
    const float* __restrict__ Opart, const float* __restrict__ MLpart,
    unsigned short* __restrict__ ctx)
{
  const int tq = blockIdx.x;
  const int hb = blockIdx.y;
  const int tid = threadIdx.x;
  const int q  = tid >> 2;
  const int dg = tid & 3;
  const int slot0 = (hb * 64 + tq) * 4;

  float mv[4], lv[4];
  float M = -1e30f;
  #pragma unroll
  for (int ci = 0; ci < 4; ++ci) {
    mv[ci] = MLpart[(size_t)(slot0 + ci) * 128 + q * 2 + 0];
    lv[ci] = MLpart[(size_t)(slot0 + ci) * 128 + q * 2 + 1];
    M = fmaxf(M, mv[ci]);
  }
  float Lsum = 0.f;
  float wgt[4];
  #pragma unroll
  for (int ci = 0; ci < 4; ++ci) {
    wgt[ci] = __expf(mv[ci] - M);
    Lsum += wgt[ci] * lv[ci];
  }
  float inv = 1.0f / Lsum;

  floatx4 a0 = (floatx4){0.f,0.f,0.f,0.f}, a1 = (floatx4){0.f,0.f,0.f,0.f};
  #pragma unroll
  for (int ci = 0; ci < 4; ++ci) {
    const float* Op = Opart + (size_t)(slot0 + ci) * 2048 + q * 32 + dg * 8;
    floatx4 o0 = *(const floatx4*)(Op);
    floatx4 o1 = *(const floatx4*)(Op + 4);
    float wv = wgt[ci];
    a0 += wv * o0;
    a1 += wv * o1;
  }
  const int b = hb >> 2, hh = hb & 3;
  size_t base = ((size_t)b * L_SEQ + tq * 64 + q) * DMODEL + hh * 32 + dg * 8;
  #pragma unroll
  for (int j = 0; j < 4; ++j) {
    ctx[base + j]     = f2bf(a0[j] * inv);
    ctx[base + 4 + j] = f2bf(a1[j] * inv);
  }
}

// ---------------------------------------------------------------------------
// Kernel 3: output projection  out = ctx @ W_O^T + b_O  (f32 out)
// ---------------------------------------------------------------------------
__global__ __launch_bounds__(256) void oproj_kernel(
    const unsigned short* __restrict__ ctx, const float* __restrict__ WO,
    const float* __restrict__ bO, float* __restrict__ out)
{
  __shared__ unsigned short Wl[128 * WLDS];
  __shared__ float bl[128];
  const int m0 = blockIdx.x * 64;
  const int tid = threadIdx.x;

  #pragma unroll
  for (int it = 0; it < 16; ++it) {
    int idx = tid + it * 256;
    int row = idx >> 5, col = (idx & 31) * 4;
    floatx4 v = *(const floatx4*)(WO + row * 128 + col);
    unsigned short* dst = Wl + row * WLDS + col;
    dst[0] = f2bf(v[0]); dst[1] = f2bf(v[1]);
    dst[2] = f2bf(v[2]); dst[3] = f2bf(v[3]);
  }
  if (tid < 128) bl[tid] = bO[tid];
  __syncthreads();

  const int w = tid >> 6, lane = tid & 63;
  const int g = lane >> 4, qi = lane & 15;

  ushort8 xf[4];
  #pragma unroll
  for (int kk = 0; kk < 4; ++kk)
    xf[kk] = *(const ushort8*)(ctx + (size_t)(m0 + w * 16 + qi) * DMODEL + kk * 32 + g * 8);

  floatx4 acc[8];
  #pragma unroll
  for (int n = 0; n < 8; ++n) acc[n] = (floatx4){0.f, 0.f, 0.f, 0.f};

  #pragma unroll
  for (int kk = 0; kk < 4; ++kk) {
    #pragma unroll
    for (int n = 0; n < 8; ++n) {
      ushort8 wf = *(const ushort8*)(Wl + (n * 16 + qi) * WLDS + kk * 32 + g * 8);
      acc[n] = MFMA(xf[kk], wf, acc[n]);
    }
  }

  #pragma unroll
  for (int n = 0; n < 8; ++n) {
    int c = n * 16 + qi;
    float bb = bl[c];
    #pragma unroll
    for (int r = 0; r < 4; ++r) {
      int m = m0 + w * 16 + 4 * g + r;
      out[(size_t)m * DMODEL + c] = acc[n][r] + bb;
    }
  }
}

// ---------------------------------------------------------------------------
extern "C" void kernel_launch(void* const* d_in, const int* in_sizes, int n_in,
                              void* d_out, int out_size, void* d_ws, size_t ws_size,
                              hipStream_t stream) {
  const float* q  = (const float*)d_in[0];
  const float* k  = (const float*)d_in[1];
  const float* v  = (const float*)d_in[2];
  const float* WQ = (const float*)d_in[3];
  const float* bQ = (const float*)d_in[4];
  const float* WK = (const float*)d_in[5];
  const float* bK = (const float*)d_in[6];
  const float* WV = (const float*)d_in[7];
  const float* bV = (const float*)d_in[8];
  const float* WO = (const float*)d_in[9];
  const float* bO = (const float*)d_in[10];
  float* out = (float*)d_out;

  const size_t plane = (size_t)BATCH * NHEAD * L_SEQ * DHEAD;  // 1,048,576 ush
  unsigned short* Qs  = (unsigned short*)d_ws;
  unsigned short* Ks  = Qs + plane;
  unsigned short* Vt  = Ks + plane;
  unsigned short* ctx = Vt + plane;                 // [B][L][128] bf16 (1M ush)
  float* Opart  = (float*)(ctx + plane);            // 2048 slots x 64 x 32 f32
  float* MLpart = Opart + (size_t)2048 * 2048;      // 2048 slots x 64 x 2 f32

  hipLaunchKernelGGL(proj_kernel, dim3(64, 2, 3), dim3(256), 0, stream,
                     q, k, v, WQ, bQ, WK, bK, WV, bV, Qs, Ks, Vt);
  hipLaunchKernelGGL(attn_kernel, dim3(16, 64), dim3(256), 0, stream,
                     Qs, Ks, Vt, Opart, MLpart);
  hipLaunchKernelGGL(combine_kernel, dim3(64, 8), dim3(256), 0, stream,
                     Opart, MLpart, ctx);
  hipLaunchKernelGGL(oproj_kernel, dim3(128), dim3(256), 0, stream, ctx, WO, bO, out);
}